// Round 8
// baseline (653.306 us; speedup 1.0000x reference)
//
#include <hip/hip_runtime.h>
#include <hip/hip_fp8.h>
#include <math.h>

#define B_ROWS 2048
#define D_K    2048
#define N_CLS  50257
#define BM     256
#define BN     256
#define BK     64
#define NT     (D_K / BK)       // 32 K-tiles
#define GM     8                // 2048/256 m-tiles
#define GN     197              // ceil(50257/256) n-tiles
#define N_PAD  (GN * BN)        // 50432
#define NWG    (GM * GN)        // 1576 = 8*197 (bijective XCD swizzle)

// LDS: B-only double buffer. Buffer b at b*16384: [256 cols][64 B] fp8,
// 16B-slot swizzle p = s ^ ((row>>1)&3). Stats at 32768.
#define BUFB   16384
#define STATS  32768

typedef __attribute__((ext_vector_type(4)))  int   i32x4;
typedef __attribute__((ext_vector_type(8)))  int   i32x8;
typedef __attribute__((ext_vector_type(16))) float f32x16;

typedef __attribute__((address_space(1))) const void as1cv;
typedef __attribute__((address_space(3))) void       as3v;

__device__ __forceinline__ void glds16(const void* g, void* l) {
  __builtin_amdgcn_global_load_lds((as1cv*)g, (as3v*)l, 16, 0, 0);
}
__device__ __forceinline__ void bar() {
  __builtin_amdgcn_sched_barrier(0);
  __builtin_amdgcn_s_barrier();
  __builtin_amdgcn_sched_barrier(0);
}

__device__ __forceinline__ unsigned char f2q(float x) {
  __hip_fp8_e4m3 q(x);
  return *reinterpret_cast<unsigned char*>(&q);
}

// ---------- W: fp32 -> fp8 e4m3, scaled x128, zero-padded to N_PAD rows ----------
__global__ void conv_w_q(const float* __restrict__ W, unsigned char* __restrict__ Wq) {
  const size_t NU = (size_t)N_PAD * D_K / 8;
  const size_t stride = (size_t)gridDim.x * blockDim.x;
  for (size_t u = (size_t)blockIdx.x * blockDim.x + threadIdx.x; u < NU; u += stride) {
    const size_t e = u * 8;
    unsigned long long pk = 0ull;
    if ((e >> 11) < (size_t)N_CLS) {
      const float4 a = *(const float4*)(W + e);
      const float4 b = *(const float4*)(W + e + 4);
      const float v[8] = {a.x, a.y, a.z, a.w, b.x, b.y, b.z, b.w};
#pragma unroll
      for (int i = 0; i < 8; ++i)
        pk |= (unsigned long long)f2q(v[i] * 128.0f) << (8 * i);
    }
    *(unsigned long long*)(Wq + e) = pk;
  }
}

// ---------- E: fp32 -> fp8 e4m3 in FRAGMENT-MAJOR layout ----------
// dst = [r5 = R>>5][t = kb>>6][rd = (kb>>4)&1][lane = ((kb>>5)&1)*32 + (R&31)][kb&15]
// so the GEMM's A-fragment load (fi, rd, tile t) is one coalesced 1-KB read.
__global__ void conv_e_q(const float* __restrict__ E, unsigned char* __restrict__ EqT) {
  const size_t NU = (size_t)B_ROWS * D_K / 8;
  const size_t stride = (size_t)gridDim.x * blockDim.x;
  for (size_t u = (size_t)blockIdx.x * blockDim.x + threadIdx.x; u < NU; u += stride) {
    const size_t R  = u >> 8;                 // row
    const int    kb = (int)(u & 255) * 8;     // k-byte offset
    const float4 a = *(const float4*)(E + R * D_K + kb);
    const float4 b = *(const float4*)(E + R * D_K + kb + 4);
    const float v[8] = {a.x, a.y, a.z, a.w, b.x, b.y, b.z, b.w};
    unsigned long long pk = 0ull;
#pragma unroll
    for (int i = 0; i < 8; ++i)
      pk |= (unsigned long long)f2q(v[i]) << (8 * i);
    const int t  = kb >> 6;
    const int lh = (kb >> 5) & 1;
    const int rd = (kb >> 4) & 1;
    const int bb = kb & 15;
    const size_t dst = (((size_t)(R >> 5) * NT + t) * 2 + rd) * 1024
                     + (size_t)(lh * 32 + (int)(R & 31)) * 16 + bb;
    *(unsigned long long*)(EqT + dst) = pk;
  }
}

// ---------- fused MX-fp8 GEMM + per-tile row stats ----------
// 256x256 tile, 8 waves (2m x 4n), per-wave 128x64 via 8x mfma_scale 32x32x64.
// A: direct global->VGPR (fragment-major, L1/L2-resident). B: LDS double-buffer.
// One vmcnt(0)+barrier per K-tile; all operand waits compiler-counted.
__global__ __launch_bounds__(512, 2) void gemm_ce(
    const unsigned char* __restrict__ EqT,
    const unsigned char* __restrict__ Wq,
    const int* __restrict__ labels,
    float* __restrict__ pm, float* __restrict__ ps, float* __restrict__ pt,
    float* __restrict__ ly)
{
  __shared__ __align__(16) char lds[STATS + 12288];
  float (*s_m)[4] = (float (*)[4])(lds + STATS);
  float (*s_s)[4] = (float (*)[4])(lds + STATS + 4096);
  float (*s_t)[4] = (float (*)[4])(lds + STATS + 8192);

  const int tid  = threadIdx.x;
  const int wid  = tid >> 6;
  const int lane = tid & 63;
  const int wm   = wid >> 2;       // 0..1 -> 128-row block
  const int wn   = wid & 3;        // 0..3 -> 64-col block
  const int l31  = lane & 31;
  const int lh   = lane >> 5;

  // XCD-aware bijective swizzle (NWG = 8*197)
  const int bid     = blockIdx.x;
  const int logical = (bid & 7) * (NWG / 8) + (bid >> 3);
  const int n_tile  = logical / GM;
  const int m_tile  = logical % GM;

  // ---- B staging: dest = q*8192 + wid*1024 + lane*16
  //      -> row = q*128 + wid*16 + (lane>>2); content slot = (lane&3)^((lane>>3)&3)
  const int srow = wid * 16 + (lane >> 2);
  const int ssw  = (((lane & 3) ^ ((lane >> 3) & 3)) << 4);
  const unsigned char* Bg = Wq + (size_t)(n_tile * BN + srow) * D_K + ssw;
  const int sdst = wid * 1024 + (lane & 63) * 16;

  // ---- B fragment LDS offsets: row = wn*64 + fj*32 + l31, slot (lh*2+rd)^rmsk ----
  const int rmsk = (l31 >> 1) & 3;
  const int lk2  = lh * 2;
  int boff[2][2];
#pragma unroll
  for (int fj = 0; fj < 2; ++fj)
#pragma unroll
    for (int rd = 0; rd < 2; ++rd)
      boff[fj][rd] = (wn * 64 + fj * 32 + l31) * 64 + (((lk2 + rd) ^ rmsk) << 4);

  // ---- A fragment global base (fragment-major EqT) ----
  const unsigned char* Ab = EqT
      + ((size_t)(m_tile * 8 + wm * 4) * NT) * 2048 + (size_t)lane * 16;
  // fa[fi][rd] at tile t: Ab + ((fi*NT + t)*2 + rd)*1024

  f32x16 acc[4][2] = {};
  union FR { i32x8 v; i32x4 h[2]; };

#define STAGE(BUF, TT)                                                      \
  do {                                                                      \
    const unsigned char* _b = Bg + (size_t)(TT) * BK;                       \
    char* _d = lds + (BUF) * BUFB + sdst;                                   \
    glds16(_b,          _d);                                                \
    glds16(_b + 262144, _d + 8192);                                         \
  } while (0)

  STAGE(0, 0);

  for (int t = 0; t < NT; ++t) {
    const char* Rb = lds + ((t & 1) ? BUFB : 0);

    asm volatile("s_waitcnt vmcnt(0)" ::: "memory");   // stage(t) landed (all waves after bar)
    bar();

    FR fb[2], fa[4];
#pragma unroll
    for (int fj = 0; fj < 2; ++fj) {
      fb[fj].h[0] = *(const i32x4*)(Rb + boff[fj][0]);
      fb[fj].h[1] = *(const i32x4*)(Rb + boff[fj][1]);
    }
#pragma unroll
    for (int fi = 0; fi < 4; ++fi) {
      fa[fi].h[0] = *(const i32x4*)(Ab + ((size_t)(fi * NT + t) * 2 + 0) * 1024);
      fa[fi].h[1] = *(const i32x4*)(Ab + ((size_t)(fi * NT + t) * 2 + 1) * 1024);
    }
    if (t < NT - 1) STAGE((t + 1) & 1, t + 1);

    __builtin_amdgcn_s_setprio(1);
#pragma unroll
    for (int fi = 0; fi < 4; ++fi)
#pragma unroll
      for (int fj = 0; fj < 2; ++fj)
        acc[fi][fj] = __builtin_amdgcn_mfma_scale_f32_32x32x64_f8f6f4(
            fa[fi].v, fb[fj].v, acc[fi][fj], 0, 0,
            0, 0x7F7F7F7F, 0, 0x7F7F7F7F);
    __builtin_amdgcn_s_setprio(0);
  }
#undef STAGE

  // ---------- epilogue: per-row (max, sumexp, sum) + label gather ----------
  // C/D 32x32: col = lane&31, row = (reg&3) + 8*(reg>>2) + 4*(lane>>5)
  const float inv = 0.0078125f;   // 1/128 (undo W pre-scale)
  const int colb = n_tile * BN + wn * 64;
  const int c0_  = colb + l31;
  const int c1_  = c0_ + 32;
  const bool ok0 = c0_ < N_CLS;
  const bool ok1 = c1_ < N_CLS;

#pragma unroll
  for (int fi = 0; fi < 4; ++fi) {
#pragma unroll
    for (int reg = 0; reg < 16; ++reg) {
      const int rt  = wm * 128 + fi * 32 + (reg & 3) + 8 * (reg >> 2) + 4 * lh;
      const int row = m_tile * BM + rt;
      const float v0 = acc[fi][0][reg] * inv;
      const float v1 = acc[fi][1][reg] * inv;
      const int lab = labels[row];
      if (lab == c0_) ly[row] = v0;
      if (lab == c1_) ly[row] = v1;

      float mx = fmaxf(ok0 ? v0 : -INFINITY, ok1 ? v1 : -INFINITY);
      float sm = (ok0 ? v0 : 0.f) + (ok1 ? v1 : 0.f);
#pragma unroll
      for (int d = 1; d < 32; d <<= 1) {
        mx = fmaxf(mx, __shfl_xor(mx, d));
        sm += __shfl_xor(sm, d);
      }
      float se = (ok0 ? __expf(v0 - mx) : 0.f) + (ok1 ? __expf(v1 - mx) : 0.f);
#pragma unroll
      for (int d = 1; d < 32; d <<= 1) se += __shfl_xor(se, d);

      if (l31 == 0) { s_m[rt][wn] = mx; s_s[rt][wn] = se; s_t[rt][wn] = sm; }
    }
  }
  __syncthreads();
  if (tid < BM) {
    float M = -INFINITY;
#pragma unroll
    for (int g = 0; g < 4; ++g) M = fmaxf(M, s_m[tid][g]);
    float S = 0.f, T = 0.f;
#pragma unroll
    for (int g = 0; g < 4; ++g) {
      S += s_s[tid][g] * __expf(s_m[tid][g] - M);
      T += s_t[tid][g];
    }
    const size_t o = (size_t)n_tile * B_ROWS + m_tile * BM + tid;
    pm[o] = M; ps[o] = S; pt[o] = T;
  }
}

// ---------- final combine: GN partials per row -> loss ----------
__global__ void ce_reduce(const float* __restrict__ pm, const float* __restrict__ ps,
                          const float* __restrict__ pt, const float* __restrict__ ly,
                          float* __restrict__ out)
{
  const int tid = threadIdx.x;
  const int row = blockIdx.x * blockDim.x + tid;
  float M = -INFINITY, S = 0.f, T = 0.f;
  for (int nt = 0; nt < GN; ++nt) {
    const size_t o = (size_t)nt * B_ROWS + row;
    const float m = pm[o], s = ps[o], t = pt[o];
    const float Mn = fmaxf(M, m);
    S = S * __expf(M - Mn) + s * __expf(m - Mn);
    M = Mn;
    T += t;
  }
  const float lse = M + logf(S);
  float per = lse - 0.9f * ly[row] - 0.1f * (T * (1.0f / (float)N_CLS));
#pragma unroll
  for (int d = 1; d < 64; d <<= 1) per += __shfl_xor(per, d);
  __shared__ float red[4];
  if ((tid & 63) == 0) red[tid >> 6] = per;
  __syncthreads();
  if (tid == 0)
    atomicAdd(out, (red[0] + red[1] + red[2] + red[3]) * (1.0f / B_ROWS));
}

extern "C" void kernel_launch(void* const* d_in, const int* in_sizes, int n_in,
                              void* d_out, int out_size, void* d_ws, size_t ws_size,
                              hipStream_t stream)
{
  const float* E      = (const float*)d_in[0];
  const int*   labels = (const int*)  d_in[1];
  const float* W      = (const float*)d_in[2];
  float* out = (float*)d_out;

  char* ws = (char*)d_ws;
  unsigned char* Wq = (unsigned char*)ws;
  size_t off = (size_t)N_PAD * D_K;                // 103,284,736 B
  unsigned char* EqT = (unsigned char*)(ws + off);
  off += (size_t)B_ROWS * D_K;                     // + 4,194,304 B
  float* pm = (float*)(ws + off); off += (size_t)GN * B_ROWS * 4;
  float* ps = (float*)(ws + off); off += (size_t)GN * B_ROWS * 4;
  float* pt = (float*)(ws + off); off += (size_t)GN * B_ROWS * 4;
  float* ly = (float*)(ws + off);                  // total ~112 MB

  hipMemsetAsync(d_out, 0, sizeof(float), stream);
  conv_w_q<<<dim3(2048), dim3(256), 0, stream>>>(W, Wq);
  conv_e_q<<<dim3(512),  dim3(256), 0, stream>>>(E, EqT);
  gemm_ce<<<dim3(NWG), dim3(512), 0, stream>>>(EqT, Wq, labels, pm, ps, pt, ly);
  ce_reduce<<<dim3(B_ROWS / 256), dim3(256), 0, stream>>>(pm, ps, pt, ly, out);
}

// Round 9
// 550.243 us; speedup vs baseline: 1.1873x; 1.1873x over previous
//
#include <hip/hip_runtime.h>
#include <hip/hip_fp8.h>
#include <math.h>

#define B_ROWS 2048
#define D_K    2048
#define N_CLS  50257
#define BM     128
#define BN     128
#define BKB    128              // K-bytes per step (fp8)
#define NT     (D_K / BKB)      // 16 K-steps
#define GM     16               // 2048/128 m-tiles
#define GN     393              // ceil(50257/128) n-tiles
#define N_PAD  (GN * BN)        // 50304
#define NWG    (GM * GN)        // 6288 = 8*786 (bijective XCD swizzle)

// LDS: single buffer. A [128 rows][128 B] at 0 (16KB), B at 16384 (16KB).
// 16-B slot swizzle within each 128-B row: position p = content_slot ^ (row&7).
#define BOFF   16384
#define STATS  32768

typedef __attribute__((ext_vector_type(4))) int   i32x4;
typedef __attribute__((ext_vector_type(8))) int   i32x8;
typedef __attribute__((ext_vector_type(4))) float f32x4;

typedef __attribute__((address_space(1))) const void as1cv;
typedef __attribute__((address_space(3))) void       as3v;

__device__ __forceinline__ void glds16(const void* g, void* l) {
  __builtin_amdgcn_global_load_lds((as1cv*)g, (as3v*)l, 16, 0, 0);
}

__device__ __forceinline__ unsigned char f2q(float x) {
  __hip_fp8_e4m3 q(x);
  return *reinterpret_cast<unsigned char*>(&q);
}

// ---------- W: fp32 -> fp8 e4m3, scaled x128, zero-padded to N_PAD rows ----------
__global__ void conv_w_q(const float* __restrict__ W, unsigned char* __restrict__ Wq) {
  const size_t NU = (size_t)N_PAD * D_K / 8;
  const size_t stride = (size_t)gridDim.x * blockDim.x;
  for (size_t u = (size_t)blockIdx.x * blockDim.x + threadIdx.x; u < NU; u += stride) {
    const size_t e = u * 8;
    unsigned long long pk = 0ull;
    if ((e >> 11) < (size_t)N_CLS) {
      const float4 a = *(const float4*)(W + e);
      const float4 b = *(const float4*)(W + e + 4);
      const float v[8] = {a.x, a.y, a.z, a.w, b.x, b.y, b.z, b.w};
#pragma unroll
      for (int i = 0; i < 8; ++i)
        pk |= (unsigned long long)f2q(v[i] * 128.0f) << (8 * i);
    }
    *(unsigned long long*)(Wq + e) = pk;
  }
}

// ---------- E: fp32 -> fp8 e4m3, row-major ----------
__global__ void conv_e_q(const float* __restrict__ E, unsigned char* __restrict__ Eq) {
  const size_t NU = (size_t)B_ROWS * D_K / 8;
  const size_t stride = (size_t)gridDim.x * blockDim.x;
  for (size_t u = (size_t)blockIdx.x * blockDim.x + threadIdx.x; u < NU; u += stride) {
    const size_t e = u * 8;
    const float4 a = *(const float4*)(E + e);
    const float4 b = *(const float4*)(E + e + 4);
    const float v[8] = {a.x, a.y, a.z, a.w, b.x, b.y, b.z, b.w};
    unsigned long long pk = 0ull;
#pragma unroll
    for (int i = 0; i < 8; ++i)
      pk |= (unsigned long long)f2q(v[i]) << (8 * i);
    *(unsigned long long*)(Eq + e) = pk;
  }
}

// ---------- fused MX-fp8 GEMM + per-tile row stats (m97/m148 structure) ----------
// 128x128 tile, 4 waves (2x2), per-wave 64x64 via 4x4 mfma_scale 16x16x128.
// Single LDS buffer, 2 __syncthreads per K-step, multi-block overlap does the
// pipelining (m114/m148). W pre-scaled x128, acc scaled 1/128 in epilogue.
__global__ __launch_bounds__(256) void gemm_ce(
    const unsigned char* __restrict__ Eq,
    const unsigned char* __restrict__ Wq,
    const int* __restrict__ labels,
    float* __restrict__ pm, float* __restrict__ ps, float* __restrict__ pt,
    float* __restrict__ ly)
{
  __shared__ __align__(16) char lds[STATS + 3072];
  float (*s_m)[2] = (float (*)[2])(lds + STATS);
  float (*s_s)[2] = (float (*)[2])(lds + STATS + 1024);
  float (*s_t)[2] = (float (*)[2])(lds + STATS + 2048);

  const int tid  = threadIdx.x;
  const int wid  = tid >> 6;
  const int lane = tid & 63;
  const int wm   = wid >> 1;       // 0..1 -> 64-row block
  const int wn   = wid & 1;        // 0..1 -> 64-col block
  const int l16  = lane & 15;
  const int lhi  = lane >> 4;      // 0..3 -> k-chunk

  // XCD-aware bijective swizzle (NWG = 8*786)
  const int bid     = blockIdx.x;
  const int logical = (bid & 7) * (NWG / 8) + (bid >> 3);
  const int n_tile  = logical / GM;   // 16 consecutive logicals share B panel
  const int m_tile  = logical % GM;

  // ---- staging: thread t, call q -> dest byte q*4096 + t*16
  //      row = q*32 + (t>>3), slot position = t&7; content slot = (t&7)^((t>>3)&7)
  const int gsw  = (((tid & 7) ^ ((tid >> 3) & 7)) << 4);
  const int srow = tid >> 3;
  const unsigned char* Ag = Eq + (size_t)(m_tile * BM + srow) * D_K + gsw;
  const unsigned char* Bg = Wq + (size_t)(n_tile * BN + srow) * D_K + gsw;
  char* const ldsA = lds;
  char* const ldsB = lds + BOFF;
  const int sdst = tid * 16;
  // +q -> +32 rows = +65536 B global; +K-step -> +128 B

  // ---- fragment read offsets: row R, k-chunk p=lhi, 2 b128 at slots (2p+rd)^(R&7)
  const int p2 = lhi * 2;
  int offA[4][2], offB[4][2];
#pragma unroll
  for (int fi = 0; fi < 4; ++fi) {
    const int R = wm * 64 + fi * 16 + l16;
#pragma unroll
    for (int rd = 0; rd < 2; ++rd)
      offA[fi][rd] = R * 128 + (((p2 + rd) ^ (R & 7)) << 4);
  }
#pragma unroll
  for (int fj = 0; fj < 4; ++fj) {
    const int C = wn * 64 + fj * 16 + l16;
#pragma unroll
    for (int rd = 0; rd < 2; ++rd)
      offB[fj][rd] = C * 128 + (((p2 + rd) ^ (C & 7)) << 4);
  }

  f32x4 acc[4][4] = {};
  union FR { i32x8 v; i32x4 h[2]; };

  for (int t = 0; t < NT; ++t) {
    const unsigned char* at = Ag + (size_t)t * BKB;
    const unsigned char* bt = Bg + (size_t)t * BKB;
#pragma unroll
    for (int q = 0; q < 4; ++q) {
      glds16(at + (size_t)q * 65536, ldsA + q * 4096 + sdst);
      glds16(bt + (size_t)q * 65536, ldsB + q * 4096 + sdst);
    }
    __syncthreads();

    FR fa[4], fb[4];
#pragma unroll
    for (int fi = 0; fi < 4; ++fi) {
      fa[fi].h[0] = *(const i32x4*)(ldsA + offA[fi][0]);
      fa[fi].h[1] = *(const i32x4*)(ldsA + offA[fi][1]);
    }
#pragma unroll
    for (int fj = 0; fj < 4; ++fj) {
      fb[fj].h[0] = *(const i32x4*)(ldsB + offB[fj][0]);
      fb[fj].h[1] = *(const i32x4*)(ldsB + offB[fj][1]);
    }
#pragma unroll
    for (int fi = 0; fi < 4; ++fi)
#pragma unroll
      for (int fj = 0; fj < 4; ++fj)
        acc[fi][fj] = __builtin_amdgcn_mfma_scale_f32_16x16x128_f8f6f4(
            fa[fi].v, fb[fj].v, acc[fi][fj], 0, 0,
            0, 0x7F7F7F7F, 0, 0x7F7F7F7F);
    __syncthreads();
  }

  // ---------- epilogue: per-row (max, sumexp, sum) + label gather ----------
  // C/D 16x16: col = lane&15, row = (lane>>4)*4 + reg  [verified m89/m91]
  const float inv = 0.0078125f;   // 1/128 (undo W pre-scale)
  const int row_base = m_tile * BM;
  const int col_base = n_tile * BN + wn * 64;

#pragma unroll
  for (int fi = 0; fi < 4; ++fi) {
#pragma unroll
    for (int r = 0; r < 4; ++r) {
      const int rt  = wm * 64 + fi * 16 + lhi * 4 + r;
      const int row = row_base + rt;
      const int lab = labels[row];
      const int rel = lab - col_base - l16;
#pragma unroll
      for (int fj = 0; fj < 4; ++fj) {
        if (rel == fj * 16) ly[row] = acc[fi][fj][r] * inv;   // static acc index
      }

      float mx = -INFINITY, sm = 0.f;
#pragma unroll
      for (int fj = 0; fj < 4; ++fj) {
        const bool v = (col_base + fj * 16 + l16) < N_CLS;
        const float x = acc[fi][fj][r] * inv;
        if (v) { mx = fmaxf(mx, x); sm += x; }
      }
#pragma unroll
      for (int d = 1; d < 16; d <<= 1) {
        mx = fmaxf(mx, __shfl_xor(mx, d));
        sm += __shfl_xor(sm, d);
      }
      float se = 0.f;
#pragma unroll
      for (int fj = 0; fj < 4; ++fj) {
        const bool v = (col_base + fj * 16 + l16) < N_CLS;
        if (v) se += __expf(acc[fi][fj][r] * inv - mx);
      }
#pragma unroll
      for (int d = 1; d < 16; d <<= 1) se += __shfl_xor(se, d);

      if (l16 == 0) { s_m[rt][wn] = mx; s_s[rt][wn] = se; s_t[rt][wn] = sm; }
    }
  }
  __syncthreads();
  if (tid < BM) {
    const float m0 = s_m[tid][0], m1 = s_m[tid][1];
    const float M = fmaxf(m0, m1);
    const float S = s_s[tid][0] * __expf(m0 - M) + s_s[tid][1] * __expf(m1 - M);
    const float T = s_t[tid][0] + s_t[tid][1];
    const size_t o = (size_t)n_tile * B_ROWS + row_base + tid;
    pm[o] = M; ps[o] = S; pt[o] = T;
  }
}

// ---------- final combine: GN partials per row -> loss ----------
__global__ void ce_reduce(const float* __restrict__ pm, const float* __restrict__ ps,
                          const float* __restrict__ pt, const float* __restrict__ ly,
                          float* __restrict__ out)
{
  const int tid = threadIdx.x;
  const int row = blockIdx.x * blockDim.x + tid;
  float M = -INFINITY, S = 0.f, T = 0.f;
  for (int nt = 0; nt < GN; ++nt) {
    const size_t o = (size_t)nt * B_ROWS + row;
    const float m = pm[o], s = ps[o], t = pt[o];
    const float Mn = fmaxf(M, m);
    S = S * __expf(M - Mn) + s * __expf(m - Mn);
    M = Mn;
    T += t;
  }
  const float lse = M + logf(S);
  float per = lse - 0.9f * ly[row] - 0.1f * (T * (1.0f / (float)N_CLS));
#pragma unroll
  for (int d = 1; d < 64; d <<= 1) per += __shfl_xor(per, d);
  __shared__ float red[4];
  if ((tid & 63) == 0) red[tid >> 6] = per;
  __syncthreads();
  if (tid == 0)
    atomicAdd(out, (red[0] + red[1] + red[2] + red[3]) * (1.0f / B_ROWS));
}

extern "C" void kernel_launch(void* const* d_in, const int* in_sizes, int n_in,
                              void* d_out, int out_size, void* d_ws, size_t ws_size,
                              hipStream_t stream)
{
  const float* E      = (const float*)d_in[0];
  const int*   labels = (const int*)  d_in[1];
  const float* W      = (const float*)d_in[2];
  float* out = (float*)d_out;

  char* ws = (char*)d_ws;
  unsigned char* Wq = (unsigned char*)ws;
  size_t off = (size_t)N_PAD * D_K;                // 103,022,592 B
  unsigned char* Eq = (unsigned char*)(ws + off);
  off += (size_t)B_ROWS * D_K;                     // + 4,194,304 B
  float* pm = (float*)(ws + off); off += (size_t)GN * B_ROWS * 4;
  float* ps = (float*)(ws + off); off += (size_t)GN * B_ROWS * 4;
  float* pt = (float*)(ws + off); off += (size_t)GN * B_ROWS * 4;
  float* ly = (float*)(ws + off);                  // total ~117 MB

  hipMemsetAsync(d_out, 0, sizeof(float), stream);
  conv_w_q<<<dim3(2048), dim3(256), 0, stream>>>(W, Wq);
  conv_e_q<<<dim3(512),  dim3(256), 0, stream>>>(E, Eq);
  gemm_ce<<<dim3(NWG), dim3(256), 0, stream>>>(Eq, Wq, labels, pm, ps, pt, ly);
  ce_reduce<<<dim3(B_ROWS / 256), dim3(256), 0, stream>>>(pm, ps, pt, ly, out);
}

// Round 10
// 513.649 us; speedup vs baseline: 1.2719x; 1.0712x over previous
//
#include <hip/hip_runtime.h>
#include <hip/hip_fp8.h>
#include <math.h>

#define B_ROWS 2048
#define D_K    2048
#define N_CLS  50257
#define BM     128
#define BN     128
#define BKB    128              // K-bytes per step (fp8)
#define NT     (D_K / BKB)      // 16 K-steps
#define GM     16               // 2048/128 m-tiles
#define GN     393              // ceil(50257/128) n-tiles
#define N_PAD  (GN * BN)        // 50304
#define NWG    (GM * GN)        // 6288 = 8*786 (bijective XCD swizzle)

// LDS: DOUBLE buffer. Buffer b at b*32768: A [128 rows][128 B] at +0 (16KB),
// B at +16384 (16KB). 16-B slot swizzle within each row: p = s ^ (row&7).
#define BUFB   32768
#define STATS  65536

typedef __attribute__((ext_vector_type(4))) int   i32x4;
typedef __attribute__((ext_vector_type(8))) int   i32x8;
typedef __attribute__((ext_vector_type(4))) float f32x4;

typedef __attribute__((address_space(1))) const void as1cv;
typedef __attribute__((address_space(3))) void       as3v;

__device__ __forceinline__ void glds16(const void* g, void* l) {
  __builtin_amdgcn_global_load_lds((as1cv*)g, (as3v*)l, 16, 0, 0);
}

__device__ __forceinline__ unsigned char f2q(float x) {
  __hip_fp8_e4m3 q(x);
  return *reinterpret_cast<unsigned char*>(&q);
}

// ---------- W: fp32 -> fp8 e4m3, scaled x128, zero-padded to N_PAD rows ----------
__global__ void conv_w_q(const float* __restrict__ W, unsigned char* __restrict__ Wq) {
  const size_t NU = (size_t)N_PAD * D_K / 8;
  const size_t stride = (size_t)gridDim.x * blockDim.x;
  for (size_t u = (size_t)blockIdx.x * blockDim.x + threadIdx.x; u < NU; u += stride) {
    const size_t e = u * 8;
    unsigned long long pk = 0ull;
    if ((e >> 11) < (size_t)N_CLS) {
      const float4 a = *(const float4*)(W + e);
      const float4 b = *(const float4*)(W + e + 4);
      const float v[8] = {a.x, a.y, a.z, a.w, b.x, b.y, b.z, b.w};
#pragma unroll
      for (int i = 0; i < 8; ++i)
        pk |= (unsigned long long)f2q(v[i] * 128.0f) << (8 * i);
    }
    *(unsigned long long*)(Wq + e) = pk;
  }
}

// ---------- E: fp32 -> fp8 e4m3, row-major ----------
__global__ void conv_e_q(const float* __restrict__ E, unsigned char* __restrict__ Eq) {
  const size_t NU = (size_t)B_ROWS * D_K / 8;
  const size_t stride = (size_t)gridDim.x * blockDim.x;
  for (size_t u = (size_t)blockIdx.x * blockDim.x + threadIdx.x; u < NU; u += stride) {
    const size_t e = u * 8;
    const float4 a = *(const float4*)(E + e);
    const float4 b = *(const float4*)(E + e + 4);
    const float v[8] = {a.x, a.y, a.z, a.w, b.x, b.y, b.z, b.w};
    unsigned long long pk = 0ull;
#pragma unroll
    for (int i = 0; i < 8; ++i)
      pk |= (unsigned long long)f2q(v[i]) << (8 * i);
    *(unsigned long long*)(Eq + e) = pk;
  }
}

// ---------- fused MX-fp8 GEMM + per-tile row stats ----------
// 128x128 tile, 4 waves (2x2), per-wave 64x64 via 4x4 mfma_scale 16x16x128.
// 2-phase double-buffer (catalog T3 minimum): STAGE(t+1) issued BEFORE
// compute(t); one __syncthreads per step (implicit vmcnt(0) = the drain).
__global__ __launch_bounds__(256) void gemm_ce(
    const unsigned char* __restrict__ Eq,
    const unsigned char* __restrict__ Wq,
    const int* __restrict__ labels,
    float* __restrict__ pm, float* __restrict__ ps, float* __restrict__ pt,
    float* __restrict__ ly)
{
  __shared__ __align__(16) char lds[STATS + 3072];
  float (*s_m)[2] = (float (*)[2])(lds + STATS);
  float (*s_s)[2] = (float (*)[2])(lds + STATS + 1024);
  float (*s_t)[2] = (float (*)[2])(lds + STATS + 2048);

  const int tid  = threadIdx.x;
  const int wid  = tid >> 6;
  const int lane = tid & 63;
  const int wm   = wid >> 1;       // 0..1 -> 64-row block
  const int wn   = wid & 1;        // 0..1 -> 64-col block
  const int l16  = lane & 15;
  const int lhi  = lane >> 4;      // 0..3 -> k-chunk

  // XCD-aware bijective swizzle (NWG = 8*786)
  const int bid     = blockIdx.x;
  const int logical = (bid & 7) * (NWG / 8) + (bid >> 3);
  const int n_tile  = logical / GM;   // 16 consecutive logicals share B panel
  const int m_tile  = logical % GM;

  // ---- staging: thread t, call q -> dest byte q*4096 + t*16
  //      row = q*32 + (t>>3), slot position = t&7; content slot = (t&7)^((t>>3)&7)
  const int gsw  = (((tid & 7) ^ ((tid >> 3) & 7)) << 4);
  const int srow = tid >> 3;
  const unsigned char* Ag = Eq + (size_t)(m_tile * BM + srow) * D_K + gsw;
  const unsigned char* Bg = Wq + (size_t)(n_tile * BN + srow) * D_K + gsw;
  const int sdst = tid * 16;
  // +q -> +32 rows = +65536 B global; +K-step -> +128 B

  // ---- fragment read offsets: row R, k-chunk p=lhi, 2 b128 at slots (2p+rd)^(R&7)
  const int p2 = lhi * 2;
  int offA[4][2], offB[4][2];
#pragma unroll
  for (int fi = 0; fi < 4; ++fi) {
    const int R = wm * 64 + fi * 16 + l16;
#pragma unroll
    for (int rd = 0; rd < 2; ++rd)
      offA[fi][rd] = R * 128 + (((p2 + rd) ^ (R & 7)) << 4);
  }
#pragma unroll
  for (int fj = 0; fj < 4; ++fj) {
    const int C = wn * 64 + fj * 16 + l16;
#pragma unroll
    for (int rd = 0; rd < 2; ++rd)
      offB[fj][rd] = 16384 + C * 128 + (((p2 + rd) ^ (C & 7)) << 4);
  }

  f32x4 acc[4][4] = {};
  union FR { i32x8 v; i32x4 h[2]; };

#define STAGE(BUF, TT)                                                     \
  do {                                                                     \
    const unsigned char* _a = Ag + (size_t)(TT) * BKB;                     \
    const unsigned char* _b = Bg + (size_t)(TT) * BKB;                     \
    char* _d = lds + (BUF) * BUFB + sdst;                                  \
    _Pragma("unroll")                                                      \
    for (int q = 0; q < 4; ++q) {                                          \
      glds16(_a + (size_t)q * 65536, _d + q * 4096);                       \
      glds16(_b + (size_t)q * 65536, _d + 16384 + q * 4096);               \
    }                                                                      \
  } while (0)

  // prologue: stage tile 0 into buf0, drain, sync
  STAGE(0, 0);
  __syncthreads();

  for (int t = 0; t < NT; ++t) {
    const char* Rb = lds + (t & 1) * BUFB;

    if (t < NT - 1) STAGE((t + 1) & 1, t + 1);   // prefetch next tile

    FR fa[4], fb[4];
#pragma unroll
    for (int fi = 0; fi < 4; ++fi) {
      fa[fi].h[0] = *(const i32x4*)(Rb + offA[fi][0]);
      fa[fi].h[1] = *(const i32x4*)(Rb + offA[fi][1]);
    }
#pragma unroll
    for (int fj = 0; fj < 4; ++fj) {
      fb[fj].h[0] = *(const i32x4*)(Rb + offB[fj][0]);
      fb[fj].h[1] = *(const i32x4*)(Rb + offB[fj][1]);
    }
#pragma unroll
    for (int fi = 0; fi < 4; ++fi)
#pragma unroll
      for (int fj = 0; fj < 4; ++fj)
        acc[fi][fj] = __builtin_amdgcn_mfma_scale_f32_16x16x128_f8f6f4(
            fa[fi].v, fb[fj].v, acc[fi][fj], 0, 0,
            0, 0x7F7F7F7F, 0, 0x7F7F7F7F);

    // end of step: implicit s_waitcnt vmcnt(0) lgkmcnt(0) + barrier.
    // Drains the prefetch issued ABOVE (it had the whole compute to land).
    __syncthreads();
  }
#undef STAGE

  // ---------- epilogue: per-row (max, sumexp, sum) + label gather ----------
  // C/D 16x16: col = lane&15, row = (lane>>4)*4 + reg  [verified m89/m91]
  const float inv = 0.0078125f;   // 1/128 (undo W pre-scale)
  const int row_base = m_tile * BM;
  const int col_base = n_tile * BN + wn * 64;

#pragma unroll
  for (int fi = 0; fi < 4; ++fi) {
#pragma unroll
    for (int r = 0; r < 4; ++r) {
      const int rt  = wm * 64 + fi * 16 + lhi * 4 + r;
      const int row = row_base + rt;
      const int lab = labels[row];
      const int rel = lab - col_base - l16;
#pragma unroll
      for (int fj = 0; fj < 4; ++fj) {
        if (rel == fj * 16) ly[row] = acc[fi][fj][r] * inv;   // static acc index
      }

      float mx = -INFINITY, sm = 0.f;
#pragma unroll
      for (int fj = 0; fj < 4; ++fj) {
        const bool v = (col_base + fj * 16 + l16) < N_CLS;
        const float x = acc[fi][fj][r] * inv;
        if (v) { mx = fmaxf(mx, x); sm += x; }
      }
#pragma unroll
      for (int d = 1; d < 16; d <<= 1) {
        mx = fmaxf(mx, __shfl_xor(mx, d));
        sm += __shfl_xor(sm, d);
      }
      float se = 0.f;
#pragma unroll
      for (int fj = 0; fj < 4; ++fj) {
        const bool v = (col_base + fj * 16 + l16) < N_CLS;
        if (v) se += __expf(acc[fi][fj][r] * inv - mx);
      }
#pragma unroll
      for (int d = 1; d < 16; d <<= 1) se += __shfl_xor(se, d);

      if (l16 == 0) { s_m[rt][wn] = mx; s_s[rt][wn] = se; s_t[rt][wn] = sm; }
    }
  }
  __syncthreads();
  if (tid < BM) {
    const float m0 = s_m[tid][0], m1 = s_m[tid][1];
    const float M = fmaxf(m0, m1);
    const float S = s_s[tid][0] * __expf(m0 - M) + s_s[tid][1] * __expf(m1 - M);
    const float T = s_t[tid][0] + s_t[tid][1];
    const size_t o = (size_t)n_tile * B_ROWS + row_base + tid;
    pm[o] = M; ps[o] = S; pt[o] = T;
  }
}

// ---------- final combine: GN partials per row -> loss ----------
__global__ void ce_reduce(const float* __restrict__ pm, const float* __restrict__ ps,
                          const float* __restrict__ pt, const float* __restrict__ ly,
                          float* __restrict__ out)
{
  const int tid = threadIdx.x;
  const int row = blockIdx.x * blockDim.x + tid;
  float M = -INFINITY, S = 0.f, T = 0.f;
  for (int nt = 0; nt < GN; ++nt) {
    const size_t o = (size_t)nt * B_ROWS + row;
    const float m = pm[o], s = ps[o], t = pt[o];
    const float Mn = fmaxf(M, m);
    S = S * __expf(M - Mn) + s * __expf(m - Mn);
    M = Mn;
    T += t;
  }
  const float lse = M + logf(S);
  float per = lse - 0.9f * ly[row] - 0.1f * (T * (1.0f / (float)N_CLS));
#pragma unroll
  for (int d = 1; d < 64; d <<= 1) per += __shfl_xor(per, d);
  __shared__ float red[4];
  if ((tid & 63) == 0) red[tid >> 6] = per;
  __syncthreads();
  if (tid == 0)
    atomicAdd(out, (red[0] + red[1] + red[2] + red[3]) * (1.0f / B_ROWS));
}

extern "C" void kernel_launch(void* const* d_in, const int* in_sizes, int n_in,
                              void* d_out, int out_size, void* d_ws, size_t ws_size,
                              hipStream_t stream)
{
  const float* E      = (const float*)d_in[0];
  const int*   labels = (const int*)  d_in[1];
  const float* W      = (const float*)d_in[2];
  float* out = (float*)d_out;

  char* ws = (char*)d_ws;
  unsigned char* Wq = (unsigned char*)ws;
  size_t off = (size_t)N_PAD * D_K;                // 103,022,592 B
  unsigned char* Eq = (unsigned char*)(ws + off);
  off += (size_t)B_ROWS * D_K;                     // + 4,194,304 B
  float* pm = (float*)(ws + off); off += (size_t)GN * B_ROWS * 4;
  float* ps = (float*)(ws + off); off += (size_t)GN * B_ROWS * 4;
  float* pt = (float*)(ws + off); off += (size_t)GN * B_ROWS * 4;
  float* ly = (float*)(ws + off);                  // total ~117 MB

  hipMemsetAsync(d_out, 0, sizeof(float), stream);
  conv_w_q<<<dim3(2048), dim3(256), 0, stream>>>(W, Wq);
  conv_e_q<<<dim3(512),  dim3(256), 0, stream>>>(E, Eq);
  gemm_ce<<<dim3(NWG), dim3(256), 0, stream>>>(Eq, Wq, labels, pm, ps, pt, ly);
  ce_reduce<<<dim3(B_ROWS / 256), dim3(256), 0, stream>>>(pm, ps, pt, ly, out);
}